// Round 12
// baseline (64.484 us; speedup 1.0000x reference)
//
#include <hip/hip_runtime.h>
#include <hip/hip_bf16.h>

typedef float f32x4 __attribute__((ext_vector_type(4)));
typedef long  l2    __attribute__((ext_vector_type(2)));

// ---------------------------------------------------------------------------
// async global->LDS, 16B per lane. LDS dest is wave-uniform base (+lane*16).
// ---------------------------------------------------------------------------
__device__ __forceinline__ void gld16(const void* g, void* l) {
    __builtin_amdgcn_global_load_lds(
        (const __attribute__((address_space(1))) void*)g,
        (__attribute__((address_space(3))) void*)l,
        16, 0, 0);
}

// gelu, tanh approximation (matches jax.nn.gelu approximate=True)
__device__ __forceinline__ float gelu_tanh(float x) {
    float u = 0.7978845608028654f * x * (1.0f + 0.044715f * x * x);
    float e = __expf(2.0f * u);
    float t = 1.0f - 2.0f / (e + 1.0f);   // tanh(u)
    return 0.5f * x * (1.0f + t);
}

// ---------------------------------------------------------------------------
// Pre-permuted fp8 storage layout (both A[M][K] and BT[N][K]) for 16x16x32:
// within each row's 64B k-segment:
//   step 1 (pair ks-halves): chunk g (16B) = orig k-bytes [g*8,+8) ++ [32+g*8,+8)
//   step 2 (chunk swizzle):  stored at chunk position c = g ^ ((row>>1)&3)
// GEMM reads one ds_read_b128 per fragment-pair (lo 8B = ks0, hi = ks1),
// conflict-free across the wave. (Verified rounds 3-10.)
// ---------------------------------------------------------------------------

// Fused quantize kernel: blocks [0, nA) do x -> Aq; blocks [nA, nA+nB) do
// w -> BTq (transpose via LDS). Single launch so the two halves overlap.
__global__ __launch_bounds__(256) void quant_fused_kernel(
        const float* __restrict__ x,  unsigned char* __restrict__ Aq,
        const float* __restrict__ w,  unsigned char* __restrict__ BTq,
        int nA, int K, int N) {
    __shared__ unsigned char lds[64 * 68];
    const int tid = threadIdx.x;

    if (blockIdx.x < nA) {
        // ---- quantA: 256 threads x float4
        int i = blockIdx.x * 256 + tid;
        float4 v = reinterpret_cast<const float4*>(x)[i];
        int pk = 0;
        pk = __builtin_amdgcn_cvt_pk_fp8_f32(v.x, v.y, pk, false);
        pk = __builtin_amdgcn_cvt_pk_fp8_f32(v.z, v.w, pk, true);
        const long k4 = (long)i * 4;
        const int  row = (int)(k4 / K);
        const int  k   = (int)(k4 % K);
        const int  o   = k & 63;
        const int  g   = (o & 31) >> 3;
        const int  s   = (o & 7) + ((o >> 5) & 1) * 8;
        const int  c   = g ^ ((row >> 1) & 3);
        *reinterpret_cast<unsigned int*>(
            Aq + (long)row * K + (k & ~63) + (c << 4) + s) = (unsigned int)pk;
        return;
    }

    // ---- quantBT: 64x64 tile transpose through LDS
    const int bid = blockIdx.x - nA;
    const int n0 = (bid & (N / 64 - 1)) * 64;
    const int k0 = (bid / (N / 64)) * 64;

    #pragma unroll
    for (int p = 0; p < 4; ++p) {
        int s = p * 256 + tid;
        int r = s >> 4;          // k within tile (0..63)
        int c = s & 15;          // float4 group (covers n = 4c..4c+3)
        float4 v = *reinterpret_cast<const float4*>(
            w + (long)(k0 + r) * N + n0 + c * 4);
        int pk = 0;
        pk = __builtin_amdgcn_cvt_pk_fp8_f32(v.x, v.y, pk, false);
        pk = __builtin_amdgcn_cvt_pk_fp8_f32(v.z, v.w, pk, true);
        *reinterpret_cast<unsigned int*>(&lds[r * 68 + c * 4]) = (unsigned int)pk;
    }
    __syncthreads();
    #pragma unroll
    for (int p = 0; p < 4; ++p) {
        int sidx = p * 256 + tid;
        int n  = sidx >> 4;      // n within tile (0..63)
        int kg = sidx & 15;      // k group of 4 (orig offset kg*4)
        unsigned int wv = 0;
        #pragma unroll
        for (int j = 0; j < 4; ++j)
            wv |= (unsigned int)lds[(kg * 4 + j) * 68 + n] << (8 * j);
        const int nn = n0 + n;
        const int o  = kg * 4;
        const int g  = (o & 31) >> 3;
        const int s  = (o & 7) + ((o >> 5) & 1) * 8;
        const int c  = g ^ ((nn >> 1) & 3);
        *reinterpret_cast<unsigned int*>(
            BTq + (long)nn * K + k0 + (c << 4) + s) = wv;
    }
}

// ---------------------------------------------------------------------------
// fp8 GEMM, persistent 2-tile blocks. Each block: two adjacent 128x128 tiles
// (same A rows). Round-10 K-loop skeleton (2 phases of 8 MFMA, A|B stages,
// boundary vmcnt(0)). Transition: stage tile-1 kt0/kt1 FIRST, then gelu +
// 32 nt scalar stores from regs, then vmcnt(32) (in-order retirement => the
// 4 oldest ops = stages are done) -> tile-1 starts with both buffers full
// while tile-0's stores drain underneath its K-loop.
// ---------------------------------------------------------------------------
__global__ __launch_bounds__(512, 8) void gemm_fp8_kernel(
        const unsigned char* __restrict__ A,   // [M][K] fp8 (permuted layout)
        const unsigned char* __restrict__ BT,  // [N][K] fp8 (permuted layout)
        const float* __restrict__ bias,        // [N]
        float* __restrict__ out,               // [M][N] f32
        int M, int N, int K) {
    constexpr int BM = 128, BN = 128, BK = 64;
    __shared__ unsigned char buf[2][(BM + BN) * BK];   // 2 x 16 KB

    const int tid  = threadIdx.x;
    const int lane = tid & 63;
    const int wid  = tid >> 6;            // 0..7
    const int wm   = wid >> 1;            // 0..3 (32 rows each)
    const int wn   = wid & 1;             // 0..1 (64 cols each)

    // Pair mapping: 512 pairs over 32x16 pair-grid (pair = 2 tiles along N).
    // 8 XCDs, each an 8x8 pair rectangle. Bijective: 512 = 8 * 64.
    const int bid = blockIdx.x;
    const int xcd = bid & 7, idx = bid >> 3;            // idx 0..63
    const int tile_m = (xcd >> 1) * 8 + (idx & 7);      // 0..31
    const int pcol   = (xcd & 1) * 8 + (idx >> 3);      // 0..15
    const int m0 = tile_m * BM;

    const int lrow = lane & 15;           // fragment row within 16
    const int kgrp = lane >> 4;           // 0..3, k-group
    const int chunkoff = ((kgrp ^ ((lrow >> 1) & 3)) << 4);

    // staging: one gld16 per thread per 8KB half (128 rows x 64B)
    const int srow   = tid >> 2;          // 0..127
    const int schunk = (tid & 3) << 4;
    const unsigned char* gA  = A  + (long)(m0 + srow) * K + schunk;
    const unsigned char* gB0 = BT + (long)(pcol * 256 + srow) * K + schunk;
    const unsigned char* gB1 = gB0 + (long)128 * K;

    const int aBase = (wm * 32 + lrow) * 64 + chunkoff;            // A rows
    const int bBase = 8192 + (wn * 64 + lrow) * 64 + chunkoff;     // B rows

    const int NT = K / BK;  // 16

#define STAGE_A(BB, TT)                                                   \
    gld16(gA + (long)(TT) * BK, &buf[BB][wid * 1024])
#define STAGE_B(BB, GB, TT)                                               \
    gld16((GB) + (long)(TT) * BK, &buf[BB][8192 + wid * 1024])

#define MFMA_Q(BJ0, BR)                                                   \
    _Pragma("unroll") for (int ks = 0; ks < 2; ++ks)                      \
    _Pragma("unroll") for (int fi = 0; fi < 2; ++fi)                      \
    _Pragma("unroll") for (int fj = 0; fj < 2; ++fj)                      \
        acc[fi][(BJ0) + fj] = __builtin_amdgcn_mfma_f32_16x16x32_fp8_fp8( \
            a01[fi][ks], BR[fj][ks], acc[fi][(BJ0) + fj], 0, 0, 0)

    #pragma unroll
    for (int rep = 0; rep < 2; ++rep) {
        const unsigned char* gB = rep ? gB1 : gB0;

        if (rep == 0) {
            STAGE_A(0, 0); STAGE_B(0, gB, 0);
            asm volatile("s_waitcnt vmcnt(0)" ::: "memory");
            __builtin_amdgcn_s_barrier();
        }
        // (rep==1: kt0 in buf0, kt1 in buf1 already staged & verified)

        f32x4 acc[2][4] = {};

        for (int t = 0; t < NT; ++t) {
            const int cur = t & 1, nxt = cur ^ 1;
            const unsigned char* sL = &buf[cur][0];
            const bool stg = (t + 1 < NT) && !(rep == 1 && t == 0);
            l2 a01[2], b01[2], b23[2];

            // ---- phase 0: stage A of t+1; reads a01,b01; MFMA cols 0-1
            if (stg) { STAGE_A(nxt, t + 1); }
            #pragma unroll
            for (int f = 0; f < 2; ++f) {
                a01[f] = *reinterpret_cast<const l2*>(sL + aBase + f * 1024);
                b01[f] = *reinterpret_cast<const l2*>(sL + bBase + f * 1024);
            }
            __builtin_amdgcn_s_barrier();
            asm volatile("s_waitcnt lgkmcnt(0)" ::: "memory");
            __builtin_amdgcn_sched_barrier(0);
            __builtin_amdgcn_s_setprio(1);
            MFMA_Q(0, b01);
            __builtin_amdgcn_s_setprio(0);

            // ---- phase 1: stage B of t+1; reads b23; MFMA cols 2-3
            if (stg) { STAGE_B(nxt, gB, t + 1); }
            #pragma unroll
            for (int f = 0; f < 2; ++f)
                b23[f] = *reinterpret_cast<const l2*>(sL + bBase + 2048 + f * 1024);
            __builtin_amdgcn_s_barrier();
            asm volatile("s_waitcnt lgkmcnt(0)" ::: "memory");
            __builtin_amdgcn_sched_barrier(0);
            __builtin_amdgcn_s_setprio(1);
            MFMA_Q(2, b23);
            __builtin_amdgcn_s_setprio(0);
            __builtin_amdgcn_sched_barrier(0);

            // ---- tile boundary
            if (t < NT - 1) {
                if (stg) { asm volatile("s_waitcnt vmcnt(0)" ::: "memory"); }
                __builtin_amdgcn_sched_barrier(0);
                __builtin_amdgcn_s_barrier();
            }
        }

        // ------------------------------------------------------------------
        // epilogue for this rep: direct reg -> global nt stores.
        // C/D frag layout: col = lrow, row = kgrp*4 + r (per 16x16 fragment).
        // ------------------------------------------------------------------
        const int col0 = pcol * 256 + rep * 128 + wn * 64 + lrow;
        float* po = out + (long)(m0 + wm * 32 + kgrp * 4) * N + col0;
        float bv[4];
        #pragma unroll
        for (int bj = 0; bj < 4; ++bj) bv[bj] = bias[col0 + bj * 16];

        if (rep == 0) {
            // all waves done reading bufs before restaging them
            __builtin_amdgcn_s_barrier();
            STAGE_A(0, 0); STAGE_B(0, gB1, 0);     // tile-1 kt0 -> buf0
            STAGE_A(1, 1); STAGE_B(1, gB1, 1);     // tile-1 kt1 -> buf1
            __builtin_amdgcn_sched_barrier(0);
        }

        #pragma unroll
        for (int ai = 0; ai < 2; ++ai)
            #pragma unroll
            for (int bj = 0; bj < 4; ++bj)
                #pragma unroll
                for (int r = 0; r < 4; ++r) {
                    float xv = acc[ai][bj][r] + bv[bj];
                    __builtin_nontemporal_store(gelu_tanh(xv),
                        po + (long)(ai * 16 + r) * N + bj * 16);
                }

        if (rep == 0) {
            // 4 stages issued before 32 stores; in-order retirement:
            // outstanding <= 32  =>  the 4 oldest (stages) are complete.
            __builtin_amdgcn_sched_barrier(0);
            asm volatile("s_waitcnt vmcnt(32)" ::: "memory");
            __builtin_amdgcn_sched_barrier(0);
            __builtin_amdgcn_s_barrier();
        }
    }
#undef STAGE_A
#undef STAGE_B
#undef MFMA_Q
}

// ---------------------------------------------------------------------------
extern "C" void kernel_launch(void* const* d_in, const int* in_sizes, int n_in,
                              void* d_out, int out_size, void* d_ws, size_t ws_size,
                              hipStream_t stream) {
    const float* x    = (const float*)d_in[0];   // [tokens][d_in]
    const float* w    = (const float*)d_in[1];   // [d_in][units]
    const float* bias = (const float*)d_in[2];   // [units]
    float* out = (float*)d_out;

    const int units  = in_sizes[2];              // 4096
    const int dmodel = in_sizes[1] / units;      // 1024
    const int tokens = in_sizes[0] / dmodel;     // 4096

    unsigned char* Aq  = (unsigned char*)d_ws;                 // [tokens][dmodel] fp8
    unsigned char* BTq = Aq + (size_t)tokens * dmodel;         // [units][dmodel] fp8

    const int nA = tokens * dmodel / 4 / 256;                  // 4096 blocks
    const int nB = (units / 64) * (dmodel / 64);               // 1024 blocks
    quant_fused_kernel<<<dim3(nA + nB), dim3(256), 0, stream>>>(
        x, Aq, w, BTq, nA, dmodel, units);

    const int npairs = (tokens / 128) * (units / 256);         // 512
    gemm_fp8_kernel<<<dim3(npairs), dim3(512), 0, stream>>>(
        Aq, BTq, bias, out, tokens, units, dmodel);
}

// Round 13
// 50.251 us; speedup vs baseline: 1.2832x; 1.2832x over previous
//
#include <hip/hip_runtime.h>
#include <hip/hip_bf16.h>

typedef float f32x4  __attribute__((ext_vector_type(4)));
typedef float f32x16 __attribute__((ext_vector_type(16)));
typedef int   i32x4  __attribute__((ext_vector_type(4)));
typedef int   i32x8  __attribute__((ext_vector_type(8)));

// ---------------------------------------------------------------------------
// async global->LDS, 16B per lane. LDS dest is wave-uniform base (+lane*16).
// ---------------------------------------------------------------------------
__device__ __forceinline__ void gld16(const void* g, void* l) {
    __builtin_amdgcn_global_load_lds(
        (const __attribute__((address_space(1))) void*)g,
        (__attribute__((address_space(3))) void*)l,
        16, 0, 0);
}

// gelu, tanh approximation (matches jax.nn.gelu approximate=True)
__device__ __forceinline__ float gelu_tanh(float x) {
    float u = 0.7978845608028654f * x * (1.0f + 0.044715f * x * x);
    float e = __expf(2.0f * u);
    float t = 1.0f - 2.0f / (e + 1.0f);   // tanh(u)
    return 0.5f * x * (1.0f + t);
}

// ---------------------------------------------------------------------------
// Pre-permuted fp8 layout for 32x32x64 f8f6f4 (A[M][K] and BT[N][K]):
// within each row's 64B k-segment (4 chunks c of 16B):
//   stored chunk position c' = c ^ ((row>>1)&3); bytes within chunk unchanged.
// MFMA operand: lane (row = lane&31, h = lane>>5) holds k = h*32 + j
// (one MX 32-block), read as 2 ds_read_b128 at chunks (2h)^x, (2h+1)^x.
// 64-lane bank spread: 8 distinct 4-bank starts x 8 lanes = minimum 8 cyc.
// ---------------------------------------------------------------------------

// Fused quantize kernel: blocks [0, nA) do x -> Aq; blocks [nA, nA+nB) do
// w -> BTq (transpose via LDS). Single launch so the two halves overlap.
__global__ __launch_bounds__(256) void quant_fused_kernel(
        const float* __restrict__ x,  unsigned char* __restrict__ Aq,
        const float* __restrict__ w,  unsigned char* __restrict__ BTq,
        int nA, int K, int N) {
    __shared__ unsigned char lds[64 * 68];
    const int tid = threadIdx.x;

    if (blockIdx.x < nA) {
        // ---- quantA: 256 threads x float4
        int i = blockIdx.x * 256 + tid;
        float4 v = reinterpret_cast<const float4*>(x)[i];
        int pk = 0;
        pk = __builtin_amdgcn_cvt_pk_fp8_f32(v.x, v.y, pk, false);
        pk = __builtin_amdgcn_cvt_pk_fp8_f32(v.z, v.w, pk, true);
        const long k4 = (long)i * 4;
        const int  row = (int)(k4 / K);
        const int  k   = (int)(k4 % K);
        const int  o   = k & 63;
        const int  c   = (o >> 4) ^ ((row >> 1) & 3);
        *reinterpret_cast<unsigned int*>(
            Aq + (long)row * K + (k & ~63) + (c << 4) + (o & 15)) = (unsigned int)pk;
        return;
    }

    // ---- quantBT: 64x64 tile transpose through LDS
    const int bid = blockIdx.x - nA;
    const int n0 = (bid & (N / 64 - 1)) * 64;
    const int k0 = (bid / (N / 64)) * 64;

    #pragma unroll
    for (int p = 0; p < 4; ++p) {
        int s = p * 256 + tid;
        int r = s >> 4;          // k within tile (0..63)
        int c = s & 15;          // float4 group (covers n = 4c..4c+3)
        float4 v = *reinterpret_cast<const float4*>(
            w + (long)(k0 + r) * N + n0 + c * 4);
        int pk = 0;
        pk = __builtin_amdgcn_cvt_pk_fp8_f32(v.x, v.y, pk, false);
        pk = __builtin_amdgcn_cvt_pk_fp8_f32(v.z, v.w, pk, true);
        *reinterpret_cast<unsigned int*>(&lds[r * 68 + c * 4]) = (unsigned int)pk;
    }
    __syncthreads();
    #pragma unroll
    for (int p = 0; p < 4; ++p) {
        int sidx = p * 256 + tid;
        int n  = sidx >> 4;      // n within tile (0..63)
        int kg = sidx & 15;      // k group of 4 (orig offset kg*4)
        unsigned int wv = 0;
        #pragma unroll
        for (int j = 0; j < 4; ++j)
            wv |= (unsigned int)lds[(kg * 4 + j) * 68 + n] << (8 * j);
        const int nn = n0 + n;
        const int c  = (kg >> 2) ^ ((nn >> 1) & 3);
        *reinterpret_cast<unsigned int*>(
            BTq + (long)nn * K + k0 + (c << 4) + ((kg & 3) * 4)) = wv;
    }
}

// ---------------------------------------------------------------------------
// fp8 GEMM with MX-scaled 32x32x64 f8f6f4 MFMA (unit scales = plain fp8
// product, 2x the non-scaled fp8 rate). 128x128 tile, BK=64, 8 waves
// (4M x 2N), wave output 32x64 (1x2 of 32x32). 2 x 16 KB LDS buffers,
// round-10 skeleton collapsed to ONE phase per K-tile:
// {stage A+B of t+1; 6 ds_read_b128; barrier; lgkm0; 2 MFMA; vmcnt0; barrier}.
// Epilogue: bias + gelu, wave-private LDS transpose [32][33], nt f32x4 stores.
// ---------------------------------------------------------------------------
__global__ __launch_bounds__(512, 4) void gemm_fp8_kernel(
        const unsigned char* __restrict__ A,   // [M][K] fp8 (permuted layout)
        const unsigned char* __restrict__ BT,  // [N][K] fp8 (permuted layout)
        const float* __restrict__ bias,        // [N]
        float* __restrict__ out,               // [M][N] f32
        int M, int N, int K) {
    constexpr int BM = 128, BN = 128, BK = 64;
    __shared__ union {
        unsigned char buf[2][(BM + BN) * BK];   // 2 x 16 KB (A 8K + B 8K each)
        float ep[8][1056];                      // epilogue 32x33 f32 per wave
    } sm;

    const int tid  = threadIdx.x;
    const int lane = tid & 63;
    const int wid  = tid >> 6;            // 0..7
    const int wm   = wid >> 1;            // 0..3 (32 rows each)
    const int wn   = wid & 1;             // 0..1 (64 cols each)

    // XCD mapping: 8 XCDs over the 32x32 tile grid, each an 8x16 rectangle
    // (~1MB A + ~2MB B per XCD L2). Bijective: 1024 = 8 * 128. (round 10)
    const int bid = blockIdx.x;
    const int xcd = bid & 7, idx = bid >> 3;            // idx 0..127
    const int tile_m = (xcd >> 1) * 8  + (idx & 7);     // 0..31
    const int tile_n = (xcd & 1) * 16 + (idx >> 3);     // 0..31
    const int m0 = tile_m * BM, n0 = tile_n * BN;

    const int l31 = lane & 31;
    const int h   = lane >> 5;            // k-half selector (MX 32-block)

    // staging: one gld16 per thread per 8KB half (128 rows x 64B)
    const int srow   = tid >> 2;          // 0..127
    const int schunk = (tid & 3) << 4;
    const unsigned char* gA = A  + (long)(m0 + srow) * K + schunk;
    const unsigned char* gB = BT + (long)(n0 + srow) * K + schunk;

    // fragment read offsets (chunk-XOR addressing)
    const int rA = wm * 32 + l31;
    const int xA = (rA >> 1) & 3;
    int offA[2], offB[2][2];
    #pragma unroll
    for (int q = 0; q < 2; ++q)
        offA[q] = rA * 64 + ((((h << 1) | q) ^ xA) << 4);
    #pragma unroll
    for (int fj = 0; fj < 2; ++fj) {
        const int rB = wn * 64 + fj * 32 + l31;
        const int xB = (rB >> 1) & 3;
        #pragma unroll
        for (int q = 0; q < 2; ++q)
            offB[fj][q] = 8192 + rB * 64 + ((((h << 1) | q) ^ xB) << 4);
    }

    f32x16 acc0 = {}, acc1 = {};

    const int NT = K / BK;  // 16

#define STAGE_A(BB, TT)                                                   \
    gld16(gA + (long)(TT) * BK, &sm.buf[BB][wid * 1024])
#define STAGE_B(BB, TT)                                                   \
    gld16(gB + (long)(TT) * BK, &sm.buf[BB][8192 + wid * 1024])

    // prologue: stage tile 0 into buf 0
    STAGE_A(0, 0); STAGE_B(0, 0);
    asm volatile("s_waitcnt vmcnt(0)" ::: "memory");
    __builtin_amdgcn_s_barrier();

    for (int t = 0; t < NT; ++t) {
        const int cur = t & 1, nxt = cur ^ 1;
        const unsigned char* sL = &sm.buf[cur][0];
        const bool stg = (t + 1 < NT);

        if (stg) { STAGE_A(nxt, t + 1); STAGE_B(nxt, t + 1); }

        i32x4 alo = *reinterpret_cast<const i32x4*>(sL + offA[0]);
        i32x4 ahi = *reinterpret_cast<const i32x4*>(sL + offA[1]);
        i32x4 b0lo = *reinterpret_cast<const i32x4*>(sL + offB[0][0]);
        i32x4 b0hi = *reinterpret_cast<const i32x4*>(sL + offB[0][1]);
        i32x4 b1lo = *reinterpret_cast<const i32x4*>(sL + offB[1][0]);
        i32x4 b1hi = *reinterpret_cast<const i32x4*>(sL + offB[1][1]);

        __builtin_amdgcn_s_barrier();
        asm volatile("s_waitcnt lgkmcnt(0)" ::: "memory");
        __builtin_amdgcn_sched_barrier(0);

        i32x8 av = __builtin_shufflevector(alo, ahi, 0, 1, 2, 3, 4, 5, 6, 7);
        i32x8 b0 = __builtin_shufflevector(b0lo, b0hi, 0, 1, 2, 3, 4, 5, 6, 7);
        i32x8 b1 = __builtin_shufflevector(b1lo, b1hi, 0, 1, 2, 3, 4, 5, 6, 7);

        __builtin_amdgcn_s_setprio(1);
        // fmt 0 = fp8 e4m3; scale 127 = 2^0 (unit) -> plain fp8 product
        acc0 = __builtin_amdgcn_mfma_scale_f32_32x32x64_f8f6f4(
            av, b0, acc0, 0, 0, 0, 127, 0, 127);
        acc1 = __builtin_amdgcn_mfma_scale_f32_32x32x64_f8f6f4(
            av, b1, acc1, 0, 0, 0, 127, 0, 127);
        __builtin_amdgcn_s_setprio(0);
        __builtin_amdgcn_sched_barrier(0);

        if (t < NT - 1) {
            asm volatile("s_waitcnt vmcnt(0)" ::: "memory");
            __builtin_amdgcn_sched_barrier(0);
            __builtin_amdgcn_s_barrier();
        }
    }

    // ------------------------------------------------------------------
    // epilogue: bias + gelu, wave-private LDS transpose, nt f32x4 stores.
    // 32x32 C/D layout: col = lane&31, row = (reg&3) + 8*(reg>>2) + 4*h.
    // ------------------------------------------------------------------
    __syncthreads();   // all K-loop LDS traffic complete; safe to reuse
    float* eplds = sm.ep[wid];
    const long rbase0 = m0 + wm * 32;

#define EPI(ACC, FJ)                                                      \
    do {                                                                  \
        const int colb = n0 + wn * 64 + (FJ) * 32;                        \
        const float bv = bias[colb + l31];                                \
        _Pragma("unroll")                                                 \
        for (int r = 0; r < 16; ++r) {                                    \
            const int row = (r & 3) + 8 * (r >> 2) + 4 * h;               \
            eplds[row * 33 + l31] = gelu_tanh(ACC[r] + bv);               \
        }                                                                 \
        asm volatile("s_waitcnt lgkmcnt(0)" ::: "memory");                \
        __builtin_amdgcn_s_barrier();                                     \
        _Pragma("unroll")                                                 \
        for (int ps = 0; ps < 4; ++ps) {                                  \
            const int rr = ps * 8 + (lane >> 3);                          \
            f32x4 v = *reinterpret_cast<const f32x4*>(                    \
                eplds + rr * 33 + (lane & 7) * 4);                        \
            __builtin_nontemporal_store(v, reinterpret_cast<f32x4*>(      \
                out + (rbase0 + rr) * N + colb + (lane & 7) * 4));        \
        }                                                                 \
        asm volatile("s_waitcnt lgkmcnt(0)" ::: "memory");                \
        __builtin_amdgcn_s_barrier();                                     \
    } while (0)

    EPI(acc0, 0);
    EPI(acc1, 1);
#undef STAGE_A
#undef STAGE_B
#undef EPI
}

// ---------------------------------------------------------------------------
extern "C" void kernel_launch(void* const* d_in, const int* in_sizes, int n_in,
                              void* d_out, int out_size, void* d_ws, size_t ws_size,
                              hipStream_t stream) {
    const float* x    = (const float*)d_in[0];   // [tokens][d_in]
    const float* w    = (const float*)d_in[1];   // [d_in][units]
    const float* bias = (const float*)d_in[2];   // [units]
    float* out = (float*)d_out;

    const int units  = in_sizes[2];              // 4096
    const int dmodel = in_sizes[1] / units;      // 1024
    const int tokens = in_sizes[0] / dmodel;     // 4096

    unsigned char* Aq  = (unsigned char*)d_ws;                 // [tokens][dmodel] fp8
    unsigned char* BTq = Aq + (size_t)tokens * dmodel;         // [units][dmodel] fp8

    const int nA = tokens * dmodel / 4 / 256;                  // 4096 blocks
    const int nB = (units / 64) * (dmodel / 64);               // 1024 blocks
    quant_fused_kernel<<<dim3(nA + nB), dim3(256), 0, stream>>>(
        x, Aq, w, BTq, nA, dmodel, units);

    const int nblocks = (tokens / 128) * (units / 128);
    gemm_fp8_kernel<<<dim3(nblocks), dim3(512), 0, stream>>>(
        Aq, BTq, bias, out, tokens, units, dmodel);
}